// Round 1
// baseline (687.577 us; speedup 1.0000x reference)
//
#include <hip/hip_runtime.h>
#include <math.h>

// Problem constants (fixed by the reference setup)
constexpr int B_  = 16;
constexpr int CH  = 512;
constexpr int HW  = 128 * 128;   // 16384
constexpr int C_  = 16;          // selected classes
constexpr int G_  = 32;          // channel groups = CH / C_
constexpr int NP  = (C_ * (C_ - 1)) / 2;  // 120 off-diagonal upper pairs

// ---------------------------------------------------------------------------
// Kernel 0: per selected class, top-G channels of |w| in descending order
// (stable tie-break by smaller index, matching jnp.argsort(-w_abs)), plus
// sigmoid(|w|) weights. One wave per class; 512 values live in registers
// (8 per lane); 32 rounds of 64-lane butterfly argmax.
// Output layout (group-major, matching perm = ch_ids.reshape(G*C)):
//   perm_tbl[k*C + j] = idx[sel[j]][k],  wgh_tbl[k*C + j] = sigmoid(|w|)
// ---------------------------------------------------------------------------
__global__ __launch_bounds__(64)
void topk_kernel(const float* __restrict__ w, const int* __restrict__ sel,
                 int* __restrict__ perm_tbl, float* __restrict__ wgh_tbl) {
  const int j    = blockIdx.x;    // class slot 0..C_-1
  const int lane = threadIdx.x;   // 0..63
  const float* wr = w + (size_t)sel[j] * CH;

  float vals[8];
#pragma unroll
  for (int i = 0; i < 8; ++i) vals[i] = fabsf(wr[lane * 8 + i]);

  for (int k = 0; k < G_; ++k) {
    // local best of 8 (ascending scan, strict > keeps smaller index on ties)
    float bv = vals[0];
    int bloc = 0;
#pragma unroll
    for (int i = 1; i < 8; ++i)
      if (vals[i] > bv) { bv = vals[i]; bloc = i; }
    int bi = lane * 8 + bloc;

    // 64-lane butterfly argmax, tie-break smaller index
#pragma unroll
    for (int m = 1; m < 64; m <<= 1) {
      float ov = __shfl_xor(bv, m);
      int   oi = __shfl_xor(bi, m);
      if (ov > bv || (ov == bv && oi < bi)) { bv = ov; bi = oi; }
    }

    if (lane == 0) {
      perm_tbl[k * C_ + j] = bi;
      wgh_tbl [k * C_ + j] = 1.0f / (1.0f + expf(-bv));
    }

    // owner removes the winner
    if ((bi >> 3) == lane) {
#pragma unroll
      for (int i = 0; i < 8; ++i)
        if ((bi & 7) == i) vals[i] = -1.0f;
    }
  }
}

// ---------------------------------------------------------------------------
// Kernel 1: one block per (b, g). 256 threads stream the 16 selected
// channels (float2, coalesced) and accumulate the 120 upper-triangular
// pair dot-products in registers. Weights (positive) factor out:
// |cov_cd| = w_c * w_d * |dot(x_c, x_d)| / (HW-1).
// ---------------------------------------------------------------------------
__global__ __launch_bounds__(256, 2)
void gram_kernel(const float* __restrict__ x, const int* __restrict__ perm_tbl,
                 const float* __restrict__ wgh_tbl, float* __restrict__ out) {
  const int bg = blockIdx.x;       // 0 .. B_*G_-1
  const int b  = bg >> 5;          // / G_
  const int g  = bg & (G_ - 1);
  const int t  = threadIdx.x;

  __shared__ int   s_ch[C_];
  __shared__ float s_w[C_];
  if (t < C_) {
    s_ch[t] = perm_tbl[g * C_ + t];
    s_w[t]  = wgh_tbl[g * C_ + t];
  }
  __syncthreads();

  const float* bb = x + (size_t)b * ((size_t)CH * HW);
  int off[C_];
#pragma unroll
  for (int c = 0; c < C_; ++c) off[c] = s_ch[c] * HW;

  float acc[NP];
#pragma unroll
  for (int i = 0; i < NP; ++i) acc[i] = 0.0f;

  // HW / (256 threads * 2 floats) = 32 iterations
  for (int it = 0; it < HW / (256 * 2); ++it) {
    const int h = (it * 256 + t) * 2;
    float2 v[C_];
#pragma unroll
    for (int c = 0; c < C_; ++c)
      v[c] = *(const float2*)(bb + off[c] + h);

    int p = 0;
#pragma unroll
    for (int c = 0; c < C_; ++c) {
#pragma unroll
      for (int d = c + 1; d < C_; ++d) {
        acc[p] = fmaf(v[c].x, v[d].x, acc[p]);
        acc[p] = fmaf(v[c].y, v[d].y, acc[p]);
        ++p;
      }
    }
  }

  // 64-lane butterfly reduce each pair accumulator
  const int lane = t & 63;
  const int wv   = t >> 6;
#pragma unroll
  for (int i = 0; i < NP; ++i) {
    float a = acc[i];
#pragma unroll
    for (int m = 1; m < 64; m <<= 1) a += __shfl_xor(a, m);
    acc[i] = a;
  }

  __shared__ float s_part[4][NP];
  if (lane == 0) {
#pragma unroll
    for (int i = 0; i < NP; ++i) s_part[wv][i] = acc[i];
  }
  __syncthreads();

  __shared__ float s_fin[128];
  if (t < 128) {
    float s = 0.0f;
    if (t < NP) {
      s = s_part[0][t] + s_part[1][t] + s_part[2][t] + s_part[3][t];
      // decode linear pair index t -> (c, d), c < d
      int cc = 0, rem = t;
      while (rem >= (C_ - 1) - cc) { rem -= (C_ - 1) - cc; ++cc; }
      int dd = cc + 1 + rem;
      s = fabsf(s) * s_w[cc] * s_w[dd];
    }
    s_fin[t] = s;
  }
  __syncthreads();

  for (int st = 64; st > 0; st >>= 1) {
    if (t < st) s_fin[t] += s_fin[t + st];
    __syncthreads();
  }

  if (t == 0) {
    // loss = sum_{b,g} sum_{c<d} w_c w_d |dot| / (NP * (HW-1) * B)
    constexpr float SCALE = 1.0f / (120.0f * 16383.0f * 16.0f);
    atomicAdd(out, s_fin[0] * SCALE);
  }
}

extern "C" void kernel_launch(void* const* d_in, const int* in_sizes, int n_in,
                              void* d_out, int out_size, void* d_ws, size_t ws_size,
                              hipStream_t stream) {
  const float* x   = (const float*)d_in[0];
  const float* w   = (const float*)d_in[1];
  const int*   sel = (const int*)d_in[2];
  float*       out = (float*)d_out;

  int*   perm_tbl = (int*)d_ws;
  float* wgh_tbl  = (float*)((char*)d_ws + CH * sizeof(int));

  // d_out is re-poisoned before every launch; zero it for the atomics.
  hipMemsetAsync(d_out, 0, sizeof(float), stream);

  hipLaunchKernelGGL(topk_kernel, dim3(C_), dim3(64), 0, stream,
                     w, sel, perm_tbl, wgh_tbl);
  hipLaunchKernelGGL(gram_kernel, dim3(B_ * G_), dim3(256), 0, stream,
                     x, perm_tbl, wgh_tbl, out);
}